// Round 8
// baseline (266.541 us; speedup 1.0000x reference)
//
#include <hip/hip_runtime.h>

#define TD_ 512
#define B_  32
#define H_  512
#define TE_ 2048

typedef __attribute__((ext_vector_type(8))) short bf16x8;
typedef __attribute__((ext_vector_type(4))) short bf16x4;
typedef __attribute__((ext_vector_type(4))) float f32x4;

__device__ __forceinline__ short f2b(float f){
  union { float f; unsigned u; } v; v.f = f;
  return (short)((v.u + 0x7fffu + ((v.u >> 16) & 1u)) >> 16);  // RNE f32->bf16
}
__device__ __forceinline__ float b2f(short s){
  union { unsigned u; float f; } v; v.u = ((unsigned)(unsigned short)s) << 16;
  return v.f;
}

__device__ __forceinline__ void gload16(const void* g, void* l){
  __builtin_amdgcn_global_load_lds((const __attribute__((address_space(1))) void*)g,
                                   (__attribute__((address_space(3))) void*)l,
                                   16, 0, 0);
}

// outputs_hidden (TD,B,H) f32 -> Abf (B,TD,H) bf16
__global__ __launch_bounds__(256) void k_cvtA(const float* __restrict__ oh,
                                              short* __restrict__ Abf){
  long base = ((long)blockIdx.x * 256 + threadIdx.x) * 4;
  int t = (int)(base >> 14);
  int rem = (int)(base & 16383);
  int b = rem >> 9, h = rem & 511;
  f32x4 v = *(const f32x4*)(oh + base);
  bf16x4 o;
  o[0]=f2b(v[0]); o[1]=f2b(v[1]); o[2]=f2b(v[2]); o[3]=f2b(v[3]);
  *(bf16x4*)(Abf + (long)b*TD_*H_ + (long)t*H_ + h) = o;
}

// encoder_out (B,H,TE) f32 -> Ebf (B,H,TE) bf16 (cast) + Ebt (B,TE,H) bf16 (transposed)
__global__ __launch_bounds__(256) void k_prep(const float* __restrict__ E,
                                              short* __restrict__ Ebf,
                                              short* __restrict__ Ebt){
  __shared__ short tile[64][72];
  int b = blockIdx.z;
  int h0 = blockIdx.y << 6, e0 = blockIdx.x << 6;
  int y = threadIdx.x >> 2;      // 0..63
  int x = threadIdx.x & 3;       // 0..3
  const float* Ein = E + ((long)b*H_ + h0 + y)*TE_ + e0 + x*16;
  short* Eo = Ebf + ((long)b*H_ + h0 + y)*TE_ + e0 + x*16;
  #pragma unroll
  for (int q=0;q<2;q++){
    f32x4 v0 = *(const f32x4*)(Ein + q*8);
    f32x4 v1 = *(const f32x4*)(Ein + q*8 + 4);
    bf16x8 o;
    o[0]=f2b(v0[0]); o[1]=f2b(v0[1]); o[2]=f2b(v0[2]); o[3]=f2b(v0[3]);
    o[4]=f2b(v1[0]); o[5]=f2b(v1[1]); o[6]=f2b(v1[2]); o[7]=f2b(v1[3]);
    *(bf16x8*)(Eo + q*8) = o;
    *(bf16x8*)(&tile[y][x*16 + q*8]) = o;
  }
  __syncthreads();
  short* Ob = Ebt + ((long)b*TE_ + e0 + y)*H_ + h0 + x*16;
  bf16x8 u0, u1;
  #pragma unroll
  for (int i2=0;i2<8;i2++) u0[i2] = tile[x*16 + i2][y];
  #pragma unroll
  for (int i2=0;i2<8;i2++) u1[i2] = tile[x*16 + 8 + i2][y];
  *(bf16x8*)(Ob) = u0;
  *(bf16x8*)(Ob + 8) = u1;
}

// BK=64 staging into [128][64] bf16 tiles, source-inverse-swizzled (verified round-3+).
#define STAGE64(Adst, Bdst, Asrc, Bsrc, lda, ldb, k0)                        \
  _Pragma("unroll")                                                          \
  for (int p=0;p<4;p++){                                                     \
    int cb = (w*4+p)*64; int c = cb + lane;                                  \
    int row = c >> 3; int cs = (c & 7) ^ (row & 7);                          \
    gload16((Asrc) + (long)row*(lda) + (k0) + cs*8, (char*)(Adst) + cb*16);  \
    gload16((Bsrc) + (long)row*(ldb) + (k0) + cs*8, (char*)(Bdst) + cb*16);  \
  }

#define FRAG_READS(Abuf, Bbuf)                                                              \
    _Pragma("unroll")                                                                       \
    for (int ks=0;ks<2;ks++){                                                               \
      bf16x8 af[4], bfr[4];                                                                 \
      _Pragma("unroll")                                                                     \
      for (int m=0;m<4;m++){                                                                \
        int r_ = wr*64 + m*16 + lr;                                                         \
        af[m] = *(const bf16x8*)((const char*)(Abuf) + r_*128 + ((ks*64 + g*16) ^ ((r_ & 7) << 4))); \
      }                                                                                     \
      _Pragma("unroll")                                                                     \
      for (int n=0;n<4;n++){                                                                \
        int r_ = wc*64 + n*16 + lr;                                                         \
        bfr[n] = *(const bf16x8*)((const char*)(Bbuf) + r_*128 + ((ks*64 + g*16) ^ ((r_ & 7) << 4))); \
      }                                                                                     \
      _Pragma("unroll")                                                                     \
      for (int m=0;m<4;m++)                                                                 \
        _Pragma("unroll")                                                                   \
        for (int n=0;n<4;n++)                                                               \
          acc[m][n] = __builtin_amdgcn_mfma_f32_16x16x32_bf16(af[m], bfr[n], acc[m][n], 0, 0, 0); \
    }

// Pure GEMM1: scores(b,t,e) bf16 = Abf @ Ebt^T (K=H). No streaming, no exp.
__global__ __launch_bounds__(256) void k_gemm1(
    const short* __restrict__ Abf, const short* __restrict__ Ebt,
    short* __restrict__ scores){
  __shared__ __align__(16) char smem[32768];
  short* As = (short*)smem;             // [128][64] bf16 = 16 KB
  short* Bs = (short*)(smem + 16384);   // [128][64] bf16 = 16 KB
  int b = blockIdx.z;
  int t0 = blockIdx.y << 7;
  int e0 = blockIdx.x << 7;
  int tid = threadIdx.x, lane = tid & 63, w = tid >> 6;
  int wr = w >> 1, wc = w & 1, g = lane >> 4, lr = lane & 15;

  const short* Ag = Abf + (long)b*TD_*H_ + (long)t0*H_;
  const short* Bg = Ebt + (long)b*TE_*H_ + (long)e0*H_;

  const f32x4 fz = {0.f,0.f,0.f,0.f};
  f32x4 acc[4][4];
  #pragma unroll
  for (int m=0;m<4;m++)
    #pragma unroll
    for (int n=0;n<4;n++) acc[m][n] = fz;

  for (int k0=0;k0<H_;k0+=64){
    __syncthreads();
    STAGE64(As, Bs, Ag, Bg, H_, H_, k0);
    __syncthreads();
    FRAG_READS(As, Bs);
  }

  __syncthreads();                       // GEMM LDS reads done; reuse As region
  float* ep = (float*)(smem + (w << 12));  // 4 KB per wave: [16][64] f32, col XOR (tr<<2)
  short* scb = scores + (long)b*TD_*TE_;

  #pragma unroll
  for (int m=0;m<4;m++){
    #pragma unroll
    for (int n=0;n<4;n++){
      #pragma unroll
      for (int r=0;r<4;r++){
        int tr = g*4 + r;
        ep[tr*64 + ((n*16 + lr) ^ (tr << 2))] = acc[m][n][r];
      }
    }
    __syncthreads();                     // publish ep before read-back
    #pragma unroll
    for (int j=0;j<4;j++){
      int tr = j*4 + (lane >> 4);
      int el = (lane & 15) * 4;
      f32x4 c4 = *(const f32x4*)(ep + tr*64 + (el ^ (tr << 2)));
      int tl = wr*64 + m*16 + tr;
      bf16x4 o;
      o[0]=f2b(c4[0]); o[1]=f2b(c4[1]); o[2]=f2b(c4[2]); o[3]=f2b(c4[3]);
      *(bf16x4*)(scb + (long)(t0 + tl)*TE_ + e0 + wc*64 + el) = o;
    }
    __syncthreads();
  }
}

// Pure stream: per (b,t) row of TE: ta=exp(scores); NS=ta+S; att=ta/S (in-place
// over scores); rs[b,t]=sum(ta/S). Fully vectorized, high occupancy.
__global__ __launch_bounds__(256) void k_stream(
    short* scores_att, const float* __restrict__ S,
    float* __restrict__ NS, float* __restrict__ rs){
  __shared__ float wsum[4];
  long row = blockIdx.x;                 // 0 .. B*TD-1
  long base = row * TE_ + threadIdx.x * 8;
  int lane = threadIdx.x & 63, w = threadIdx.x >> 6;

  bf16x8 sv8 = *(const bf16x8*)(scores_att + base);
  f32x4 s0 = *(const f32x4*)(S + base);
  f32x4 s1 = *(const f32x4*)(S + base + 4);
  f32x4 ns0, ns1; bf16x8 ab; float rp = 0.f;
  #pragma unroll
  for (int i=0;i<4;i++){
    float ta = __expf(b2f(sv8[i]));
    ns0[i] = ta + s0[i];
    float av = ta * __builtin_amdgcn_rcpf(s0[i]);
    ab[i] = f2b(av); rp += av;
  }
  #pragma unroll
  for (int i=0;i<4;i++){
    float ta = __expf(b2f(sv8[4+i]));
    ns1[i] = ta + s1[i];
    float av = ta * __builtin_amdgcn_rcpf(s1[i]);
    ab[4+i] = f2b(av); rp += av;
  }
  *(f32x4*)(NS + base) = ns0;
  *(f32x4*)(NS + base + 4) = ns1;
  *(bf16x8*)(scores_att + base) = ab;    // att overwrites scores in place

  rp += __shfl_xor(rp, 1);  rp += __shfl_xor(rp, 2);
  rp += __shfl_xor(rp, 4);  rp += __shfl_xor(rp, 8);
  rp += __shfl_xor(rp, 16); rp += __shfl_xor(rp, 32);
  if (lane == 0) wsum[w] = rp;
  __syncthreads();
  if (threadIdx.x == 0) rs[row] = wsum[0] + wsum[1] + wsum[2] + wsum[3];
}

// GEMM2: ctx[t,h] = (att[t,:].Ebf[h,:]) * invRs[t], K=TE. Output (TD,B,H).
__global__ __launch_bounds__(256) void k_ctx(
    const short* __restrict__ att, const short* __restrict__ Ebf,
    const float* __restrict__ rs, float* __restrict__ ctx){
  __shared__ __align__(16) char smem[32768];
  __shared__ float invRs[128];
  short* As = (short*)smem;
  short* Bs = (short*)(smem + 16384);
  int b = blockIdx.z;
  int t0 = blockIdx.y << 7;
  int h0 = blockIdx.x << 7;
  int tid = threadIdx.x, lane = tid & 63, w = tid >> 6;
  int wr = w >> 1, wc = w & 1, g = lane >> 4, lr = lane & 15;

  if (tid < 128)
    invRs[tid] = __builtin_amdgcn_rcpf(rs[(long)b*TD_ + t0 + tid]);

  const short* Ag = att + (long)b*TD_*TE_ + (long)t0*TE_;
  const short* Bg = Ebf + (long)b*H_*TE_ + (long)h0*TE_;

  const f32x4 fz = {0.f,0.f,0.f,0.f};
  f32x4 acc[4][4];
  #pragma unroll
  for (int m=0;m<4;m++)
    #pragma unroll
    for (int n=0;n<4;n++) acc[m][n] = fz;

  for (int k0=0;k0<TE_;k0+=64){
    __syncthreads();
    STAGE64(As, Bs, Ag, Bg, TE_, TE_, k0);
    __syncthreads();
    FRAG_READS(As, Bs);
  }

  __syncthreads();
  float* ep = (float*)(smem + (w << 12));

  #pragma unroll
  for (int m=0;m<4;m++){
    #pragma unroll
    for (int n=0;n<4;n++){
      #pragma unroll
      for (int r=0;r<4;r++){
        int tr = g*4 + r;
        ep[tr*64 + ((n*16 + lr) ^ (tr << 2))] = acc[m][n][r];
      }
    }
    __syncthreads();                     // publish ep before read-back
    #pragma unroll
    for (int j=0;j<4;j++){
      int tr = j*4 + (lane >> 4);
      int hl = (lane & 15) * 4;
      f32x4 c4 = *(const f32x4*)(ep + tr*64 + (hl ^ (tr << 2)));
      int tl = wr*64 + m*16 + tr;
      float inv = invRs[tl];
      c4[0]*=inv; c4[1]*=inv; c4[2]*=inv; c4[3]*=inv;
      *(f32x4*)(ctx + (long)(t0 + tl)*B_*H_ + (long)b*H_ + h0 + wc*64 + hl) = c4;
    }
    __syncthreads();
  }
}

extern "C" void kernel_launch(void* const* d_in, const int* in_sizes, int n_in,
                              void* d_out, int out_size, void* d_ws, size_t ws_size,
                              hipStream_t stream){
  const float* oh = (const float*)d_in[0];   // (TD,B,H)
  const float* E  = (const float*)d_in[1];   // (B,H,TE)
  const float* S  = (const float*)d_in[2];   // (B,TD,TE)
  float* out_ctx = (float*)d_out;                       // (TD,B,H)
  float* out_ns  = out_ctx + (long)TD_*B_*H_;           // (B,TD,TE)

  char* ws = (char*)d_ws;
  size_t offEbt = 0;
  size_t offEbf = offEbt + (size_t)B_*TE_*H_*2;   // 64 MiB
  size_t offA   = offEbf + (size_t)B_*H_*TE_*2;   // 64 MiB
  size_t offSc  = offA   + (size_t)B_*TD_*H_*2;   // 16 MiB
  size_t offRs  = offSc  + (size_t)B_*TD_*TE_*2;  // 64 MiB (scores, then att in-place)
  short* Ebt  = (short*)(ws + offEbt);
  short* Ebf  = (short*)(ws + offEbf);
  short* Abf  = (short*)(ws + offA);
  short* scat = (short*)(ws + offSc);             // scores -> att (in place)
  float* rs   = (float*)(ws + offRs);             // [B][TD] f32

  k_cvtA<<<dim3((TD_*B_*H_)/(256*4)), 256, 0, stream>>>(oh, Abf);
  k_prep<<<dim3(TE_/64, H_/64, B_), 256, 0, stream>>>(E, Ebf, Ebt);
  k_gemm1<<<dim3(TE_/128, TD_/128, B_), 256, 0, stream>>>(Abf, Ebt, scat);
  k_stream<<<dim3(B_*TD_), 256, 0, stream>>>(scat, S, out_ns, rs);
  k_ctx<<<dim3(H_/128, TD_/128, B_), 256, 0, stream>>>(scat, Ebf, rs, out_ctx);
}